// Round 25
// baseline (194.370 us; speedup 1.0000x reference)
//
#include <hip/hip_runtime.h>
#include <math.h>

#define N_ROWS   65536
#define DIM      256
#define KCODES   1024
#define Q_SIZE   (N_ROWS * DIM)          // 16777216
#define OUT_LOSS Q_SIZE
#define OUT_PERP (Q_SIZE + 1)
#define OUT_IDX  (Q_SIZE + 2)

// flag threshold in scaled-score units (s' = 2^20 * d2-units). Same as r8 (passed).
#define TAUP 200.0f

// ws layout (bytes)
#define WS_LOSS   0        // double
#define WS_RCNT   8        // int
#define WS_TICK   12       // int (k_out last-block ticket)
#define WS_E2     16       // float[1024]  original units
#define WS_E2P    4112     // float[1024]  scaled by 2^20
#define WS_COUNTS 8208     // int[1024]
#define WS_IDX    12304    // int[65536]
#define WS_RLIST  274448   // int[65536]
#define WS_ET     536592   // float[262144]   E^T fp32 (refine)
#define WS_P      1585168  // _Float16[262144] packed f16(1024*E), tile-linear

typedef _Float16 half8 __attribute__((ext_vector_type(8)));
typedef _Float16 half4 __attribute__((ext_vector_type(4)));
typedef float    f32x4 __attribute__((ext_vector_type(4)));

#define ROWB 528    // LDS bytes per X row during A-load phase: 512 + 16 pad
#define RPB  128    // rows per block (r21-optimal: 2 blocks/CU)

// k_main LDS: [0,49152) X-staging REUSED as 3-slot B rotation; [49152,53248) e2p.
#define LDS_E2 49152

// ---------------------------------------------------------------------------
// prep: e2, e2p, Et (fp32 transpose), packed P; zero accums + ticket.
// P layout (tile-linear): tile T = codes [T*32,T*32+32), 32 tiles.
// chunk c = nt*8+kk. o = ((T*16+c)*64+lane)*8+j; code = T*32+nt*16+(lane&15),
// d = (lane>>4)*8 + kk*32 + j. Each 1KB chunk lane-linear (GLL-ready).
// grid 1024 x 256
__global__ void k_prep(const float* __restrict__ E, float* __restrict__ e2,
                       float* __restrict__ e2p, float* __restrict__ Et,
                       _Float16* __restrict__ P,
                       int* __restrict__ counts, double* __restrict__ loss,
                       int* __restrict__ rcnt, int* __restrict__ tick) {
    int b = blockIdx.x, t = threadIdx.x;
    __shared__ double red[256];
    float v = E[b * DIM + t];
    red[t] = (double)v * (double)v;

    {   // packed B-stream write (tile-linear)
        int o    = b * 256 + t;
        int j    = o & 7;
        int lane = (o >> 3) & 63;
        int c    = (o >> 9) & 15;
        int T    = o >> 13;
        int nt = c >> 3, kk = c & 7;
        int code = T * 32 + nt * 16 + (lane & 15);
        int d    = (lane >> 4) * 8 + kk * 32 + j;
        P[o] = (_Float16)(E[code * DIM + d] * 1024.0f);   // exact scaling, RN
    }

    __syncthreads();
    for (int s = 128; s > 0; s >>= 1) {
        if (t < s) red[t] += red[t + s];
        __syncthreads();
    }
    if (t == 0) { e2[b] = (float)red[0]; e2p[b] = (float)(red[0] * 1048576.0); }

    int o = b * 256 + t;
    int d = o >> 10, k = o & 1023;
    Et[o] = E[k * DIM + d];

    if (b < 4) counts[b * 256 + t] = 0;
    if (b == 0 && t == 0) { *loss = 0.0; *rcnt = 0; *tick = 0; }
}

// ---------------------------------------------------------------------------
// main (r21-exact, 70µs reproduced x3): A-in-registers GEMM, RPB=128,
// 3-slot B rotation with counted vmcnt + raw s_barrier pipeline.
// Numerics bit-identical to r8-r24.
// grid 512 x 256
__global__ void __launch_bounds__(256)
k_main(const float* __restrict__ X, const _Float16* __restrict__ P,
       const float* __restrict__ e2p,
       int* __restrict__ idx_ws, int* __restrict__ rlist,
       int* __restrict__ rcnt) {
    __shared__ __align__(16) char sAll[53248];
    const int tid  = threadIdx.x;
    const int wid  = tid >> 6;
    const int lane = tid & 63;
    const int c16  = lane & 15;
    const int kg   = lane >> 4;
    const int rb   = blockIdx.x * RPB;

    char* sX = sAll;
    char* sB = sAll;
    const float* sE2 = (const float*)(sAll + LDS_E2);

    ((f32x4*)(sAll + LDS_E2))[tid] = ((const f32x4*)e2p)[tid];

    {
        const f32x4* Xg = (const f32x4*)(X + (size_t)rb * DIM);
        #pragma unroll
        for (int it = 0; it < 16; ++it) {
            int f = it * 256 + tid;
            int row = f >> 6, d4 = f & 63;
            f32x4 v = __builtin_nontemporal_load(&Xg[(size_t)row * 64 + d4]);
            half4 hh = {(_Float16)v[0], (_Float16)v[1], (_Float16)v[2], (_Float16)v[3]};
            *(half4*)(sX + row * ROWB + d4 * 8) = hh;
        }
    }
    __syncthreads();
    half8 ar[2][8];
    if (wid < 2) {
        #pragma unroll
        for (int mt = 0; mt < 2; ++mt)
            #pragma unroll
            for (int kk = 0; kk < 8; ++kk)
                ar[mt][kk] = *(const half8*)(sX + (wid * 32 + mt * 16 + c16) * ROWB
                                             + kk * 64 + kg * 16);
    }
    __syncthreads();
    {
        const f32x4* Xg = (const f32x4*)(X + (size_t)(rb + 64) * DIM);
        #pragma unroll
        for (int it = 0; it < 16; ++it) {
            int f = it * 256 + tid;
            int row = f >> 6, d4 = f & 63;
            f32x4 v = __builtin_nontemporal_load(&Xg[(size_t)row * 64 + d4]);
            half4 hh = {(_Float16)v[0], (_Float16)v[1], (_Float16)v[2], (_Float16)v[3]};
            *(half4*)(sX + row * ROWB + d4 * 8) = hh;
        }
    }
    __syncthreads();
    if (wid >= 2) {
        #pragma unroll
        for (int mt = 0; mt < 2; ++mt)
            #pragma unroll
            for (int kk = 0; kk < 8; ++kk)
                ar[mt][kk] = *(const half8*)(sX + ((wid - 2) * 32 + mt * 16 + c16) * ROWB
                                             + kk * 64 + kg * 16);
    }
    __syncthreads();

#define STAGE(T)                                                                             \
    {                                                                                        \
        const char* src_ = (const char*)P + (size_t)(T) * 16384 + (size_t)(wid * 4) * 1024   \
                           + (size_t)lane * 16;                                              \
        char* dst_ = sB + ((T) % 3) * 16384 + (wid * 4) * 1024;                              \
        __builtin_amdgcn_global_load_lds((const __attribute__((address_space(1))) unsigned int*)(src_),          \
                                         (__attribute__((address_space(3))) unsigned int*)(dst_), 16, 0, 0);     \
        __builtin_amdgcn_global_load_lds((const __attribute__((address_space(1))) unsigned int*)(src_ + 1024),   \
                                         (__attribute__((address_space(3))) unsigned int*)(dst_ + 1024), 16, 0, 0);\
        __builtin_amdgcn_global_load_lds((const __attribute__((address_space(1))) unsigned int*)(src_ + 2048),   \
                                         (__attribute__((address_space(3))) unsigned int*)(dst_ + 2048), 16, 0, 0);\
        __builtin_amdgcn_global_load_lds((const __attribute__((address_space(1))) unsigned int*)(src_ + 3072),   \
                                         (__attribute__((address_space(3))) unsigned int*)(dst_ + 3072), 16, 0, 0);\
    }
#define SB0 __builtin_amdgcn_sched_barrier(0)

    float tb1[8], tb2[8];
    int   ti1[8];
    #pragma unroll
    for (int i = 0; i < 8; ++i) { tb1[i] = 3.4e38f; tb2[i] = 3.4e38f; ti1[i] = 0; }

    f32x4 acc[2][2];

    STAGE(0); STAGE(1);
    SB0;

    #pragma unroll 2
    for (int T = 0; T < 32; ++T) {
        if (T <= 30) { asm volatile("s_waitcnt vmcnt(4)" ::: "memory"); }
        else         { asm volatile("s_waitcnt vmcnt(0)" ::: "memory"); }
        SB0;
        __builtin_amdgcn_s_barrier();
        SB0;
        if (T < 30) STAGE(T + 2);
        SB0;

        #pragma unroll
        for (int mt = 0; mt < 2; ++mt)
            #pragma unroll
            for (int nt = 0; nt < 2; ++nt) acc[mt][nt] = 0.0f;

        const char* bbuf = sB + (T % 3) * 16384 + (size_t)lane * 16;
        #pragma unroll
        for (int kk = 0; kk < 8; ++kk) {
            half8 b0 = *(const half8*)(bbuf + (0 * 8 + kk) * 1024);
            half8 b1 = *(const half8*)(bbuf + (1 * 8 + kk) * 1024);
            acc[0][0] = __builtin_amdgcn_mfma_f32_16x16x32_f16(ar[0][kk], b0, acc[0][0], 0, 0, 0);
            acc[0][1] = __builtin_amdgcn_mfma_f32_16x16x32_f16(ar[0][kk], b1, acc[0][1], 0, 0, 0);
            acc[1][0] = __builtin_amdgcn_mfma_f32_16x16x32_f16(ar[1][kk], b0, acc[1][0], 0, 0, 0);
            acc[1][1] = __builtin_amdgcn_mfma_f32_16x16x32_f16(ar[1][kk], b1, acc[1][1], 0, 0, 0);
        }

        #pragma unroll
        for (int nt = 0; nt < 2; ++nt) {
            const int code = T * 32 + nt * 16 + c16;
            const float e2v = sE2[code];
            #pragma unroll
            for (int mt = 0; mt < 2; ++mt)
                #pragma unroll
                for (int r = 0; r < 4; ++r) {
                    float sc = fmaf(-2048.0f, acc[mt][nt][r], e2v);
                    int ix = mt * 4 + r;
                    tb2[ix] = __builtin_amdgcn_fmed3f(tb1[ix], tb2[ix], sc);
                    bool lt = sc < tb1[ix];
                    tb1[ix] = lt ? sc : tb1[ix];
                    ti1[ix] = lt ? code : ti1[ix];
                }
        }
        SB0;
    }
#undef STAGE
#undef SB0

    #pragma unroll
    for (int ix = 0; ix < 8; ++ix) {
        float v1 = tb1[ix], v2 = tb2[ix];
        int   j1 = ti1[ix];
        #pragma unroll
        for (int m = 1; m < 16; m <<= 1) {
            float ov1 = __shfl_xor(v1, m, 64);
            int   oj1 = __shfl_xor(j1, m, 64);
            float ov2 = __shfl_xor(v2, m, 64);
            bool take = (ov1 < v1) || (ov1 == v1 && oj1 < j1);
            float losr = take ? v1 : ov1;
            v1 = take ? ov1 : v1;
            j1 = take ? oj1 : j1;
            v2 = fminf(fminf(v2, ov2), losr);
        }
        tb1[ix] = v1; tb2[ix] = v2; ti1[ix] = j1;
    }
    if (c16 == 0) {
        #pragma unroll
        for (int ix = 0; ix < 8; ++ix) {
            int row = wid * 32 + (ix >> 2) * 16 + kg * 4 + (ix & 3);
            int g = rb + row;
            idx_ws[g] = ti1[ix];
            if (tb2[ix] - tb1[ix] < TAUP) {
                int slot = atomicAdd(rcnt, 1);
                rlist[slot] = g;
            }
        }
    }
}

// ---------------------------------------------------------------------------
// refine: exact reference-fp32 replication, 4 rows per Et sweep, d-loop
// unrolled x4, grid 1024 (r12/r13-proven, 58.7µs measured r15 — best of the
// four refine structures tried r15/r18/r23/r24). fp64 accumulation order per
// accumulator UNCHANGED.
// grid 1024 x 256
__launch_bounds__(256, 1)
__global__ void k_refine(const float* __restrict__ X, const float* __restrict__ Et,
                         const float* __restrict__ e2,
                         const int* __restrict__ rlist, const int* __restrict__ rcnt,
                         int* __restrict__ idx_ws) {
    __shared__ float xs[4][256];
    __shared__ float sbv[4][256];
    __shared__ int   sbi[4][256];
    __shared__ float x2s[4];
    __shared__ int   rows[4];
    const int cnt = *rcnt;
    const int t = threadIdx.x;
    for (int base = blockIdx.x * 4; base < cnt; base += gridDim.x * 4) {
        __syncthreads();
        if (t < 4) {
            int e = base + t;
            rows[t] = rlist[e < cnt ? e : (cnt - 1)];
        }
        __syncthreads();
        ((float4*)xs[t >> 6])[t & 63] =
            ((const float4*)(X + (size_t)rows[t >> 6] * DIM))[t & 63];
        __syncthreads();
        if (t < 4) {
            double s = 0.0;
            for (int d = 0; d < DIM; ++d) { double xv = (double)xs[t][d]; s += xv * xv; }
            x2s[t] = (float)s;
        }
        __syncthreads();

        double a0[4], a1[4], a2[4], a3[4];
        #pragma unroll
        for (int r = 0; r < 4; ++r) { a0[r] = 0.0; a1[r] = 0.0; a2[r] = 0.0; a3[r] = 0.0; }
        #pragma unroll 4
        for (int d = 0; d < DIM; ++d) {
            double e0 = (double)Et[d * KCODES + t];
            double e1 = (double)Et[d * KCODES + 256 + t];
            double e2d = (double)Et[d * KCODES + 512 + t];
            double e3 = (double)Et[d * KCODES + 768 + t];
            #pragma unroll
            for (int r = 0; r < 4; ++r) {
                double xv = (double)xs[r][d];
                a0[r] += xv * e0;
                a1[r] += xv * e1;
                a2[r] += xv * e2d;
                a3[r] += xv * e3;
            }
        }

        const float eA = e2[t], eB = e2[256 + t], eC = e2[512 + t], eD = e2[768 + t];
        #pragma unroll
        for (int r = 0; r < 4; ++r) {
            float best = 3.4e38f; int bk = 0;
            float x2 = x2s[r];
            { float d2 = fmaf(-2.f, (float)a0[r], x2 + eA); if (d2 < best) { best = d2; bk = t; } }
            { float d2 = fmaf(-2.f, (float)a1[r], x2 + eB); if (d2 < best) { best = d2; bk = 256 + t; } }
            { float d2 = fmaf(-2.f, (float)a2[r], x2 + eC); if (d2 < best) { best = d2; bk = 512 + t; } }
            { float d2 = fmaf(-2.f, (float)a3[r], x2 + eD); if (d2 < best) { best = d2; bk = 768 + t; } }
            sbv[r][t] = best; sbi[r][t] = bk;
        }
        __syncthreads();
        {
            const int w = t >> 6, lane = t & 63;
            float v = sbv[w][lane];     int id = sbi[w][lane];
            #pragma unroll
            for (int c = 1; c < 4; ++c) {
                float ov = sbv[w][lane + 64 * c]; int oi = sbi[w][lane + 64 * c];
                if (ov < v || (ov == v && oi < id)) { v = ov; id = oi; }
            }
            #pragma unroll
            for (int m = 1; m < 64; m <<= 1) {
                float ov = __shfl_xor(v, m, 64);
                int   oi = __shfl_xor(id, m, 64);
                if (ov < v || (ov == v && oi < id)) { v = ov; id = oi; }
            }
            if (lane == 0 && base + w < cnt) idx_ws[rows[w]] = id;
        }
    }
}

// ---------------------------------------------------------------------------
// out (+fused fin): quantized rows, index output, loss, histogram; the last
// block to finish (device-scope ticket + threadfence — dispatch-order
// independent) computes the perplexity/loss scalars. counts/loss read back
// via atomic-add-zero (explicit device-scope coherence across XCDs).
// grid 1024 x 256
__launch_bounds__(256)
__global__ void k_out(const float* __restrict__ X, const float* __restrict__ E,
                      const int* __restrict__ idx_ws, float* __restrict__ out,
                      int* __restrict__ counts, double* __restrict__ loss,
                      int* __restrict__ tick) {
    const int tid = threadIdx.x;
    const int w = tid >> 6, lane = tid & 63;
    const int rbase = blockIdx.x * 64;
    double ls = 0.0;
    #pragma unroll 4
    for (int it = 0; it < 16; ++it) {
        const int row = rbase + it * 4 + w;
        const int k = idx_ws[row];
        float4 q = ((const float4*)(E + (size_t)k * DIM))[lane];
        float4 x = ((const float4*)(X + (size_t)row * DIM))[lane];
        ((float4*)(out + (size_t)row * DIM))[lane] = q;
        double d0 = (double)q.x - (double)x.x;
        double d1 = (double)q.y - (double)x.y;
        double d2 = (double)q.z - (double)x.z;
        double d3 = (double)q.w - (double)x.w;
        ls += d0 * d0 + d1 * d1 + d2 * d2 + d3 * d3;
        if (lane == 0) {
            atomicAdd(&counts[k], 1);
            out[OUT_IDX + row] = (float)k;
        }
    }
    __shared__ double red[256];
    __shared__ int isLast;
    red[tid] = ls;
    __syncthreads();
    for (int s = 128; s > 0; s >>= 1) {
        if (tid < s) red[tid] += red[tid + s];
        __syncthreads();
    }
    if (tid == 0) {
        atomicAdd(loss, red[0]);
        __threadfence();
        int tk = atomicAdd(tick, 1);
        isLast = (tk == (int)gridDim.x - 1);
    }
    __syncthreads();
    if (isLast) {
        // fin: all blocks' counts/loss atomics are complete (ticket ordering)
        double h = 0.0;
        #pragma unroll
        for (int i = 0; i < 4; ++i) {
            int c = atomicAdd(&counts[tid + i * 256], 0);   // coherent read
            double p = (double)c / (double)N_ROWS;
            h += p * log(p + 1e-10);
        }
        red[tid] = h;
        __syncthreads();
        for (int s = 128; s > 0; s >>= 1) {
            if (tid < s) red[tid] += red[tid + s];
            __syncthreads();
        }
        if (tid == 0) {
            double lv = atomicAdd(loss, 0.0);               // coherent read
            out[OUT_PERP] = (float)exp(-red[0]);
            out[OUT_LOSS] = (float)(lv / (double)Q_SIZE * 1.25);
        }
    }
}

// ---------------------------------------------------------------------------
extern "C" void kernel_launch(void* const* d_in, const int* in_sizes, int n_in,
                              void* d_out, int out_size, void* d_ws, size_t ws_size,
                              hipStream_t stream) {
    (void)in_sizes; (void)n_in; (void)out_size; (void)ws_size;
    const float* X = (const float*)d_in[0];
    const float* E = (const float*)d_in[1];
    float* out = (float*)d_out;
    char* ws = (char*)d_ws;

    double*    loss   = (double*)(ws + WS_LOSS);
    int*       rcnt   = (int*)(ws + WS_RCNT);
    int*       tick   = (int*)(ws + WS_TICK);
    float*     e2     = (float*)(ws + WS_E2);
    float*     e2p    = (float*)(ws + WS_E2P);
    int*       counts = (int*)(ws + WS_COUNTS);
    int*       idx_ws = (int*)(ws + WS_IDX);
    int*       rlist  = (int*)(ws + WS_RLIST);
    float*     Et     = (float*)(ws + WS_ET);
    _Float16*  Pp     = (_Float16*)(ws + WS_P);

    k_prep<<<1024, 256, 0, stream>>>(E, e2, e2p, Et, Pp, counts, loss, rcnt, tick);
    k_main<<<N_ROWS / RPB, 256, 0, stream>>>(X, Pp, e2p, idx_ws, rlist, rcnt);
    k_refine<<<1024, 256, 0, stream>>>(X, Et, e2, rlist, rcnt, idx_ws);
    k_out<<<1024, 256, 0, stream>>>(X, E, idx_ws, out, counts, loss, tick);
}

// Round 26
// 165.250 us; speedup vs baseline: 1.1762x; 1.1762x over previous
//
#include <hip/hip_runtime.h>
#include <math.h>

#define N_ROWS   65536
#define DIM      256
#define KCODES   1024
#define Q_SIZE   (N_ROWS * DIM)          // 16777216
#define OUT_LOSS Q_SIZE
#define OUT_PERP (Q_SIZE + 1)
#define OUT_IDX  (Q_SIZE + 2)

// flag threshold in scaled-score units (s' = 2^20 * d2-units). Same as r8 (passed).
#define TAUP 200.0f

// ws layout (bytes)
#define WS_LOSS   0        // double
#define WS_RCNT   8        // int
#define WS_E2     16       // float[1024]  original units
#define WS_E2P    4112     // float[1024]  scaled by 2^20
#define WS_COUNTS 8208     // int[1024]
#define WS_IDX    12304    // int[65536]
#define WS_RLIST  274448   // int[65536]
#define WS_ET     536592   // float[262144]   E^T fp32 (refine)
#define WS_P      1585168  // _Float16[262144] packed f16(1024*E), tile-linear

typedef _Float16 half8 __attribute__((ext_vector_type(8)));
typedef _Float16 half4 __attribute__((ext_vector_type(4)));
typedef float    f32x4 __attribute__((ext_vector_type(4)));

#define ROWB 528    // LDS bytes per X row during A-load phase: 512 + 16 pad
#define RPB  128    // rows per block (r21-optimal: 2 blocks/CU, 8 waves/CU)

// k_main LDS: [0,49152) = X-staging region (phase 1/2) REUSED as 3-slot B
// rotation buffer [3][16384]; [49152,53248) e2p.
#define LDS_E2 49152

// ---------------------------------------------------------------------------
// prep: e2, e2p, Et (fp32 transpose, refine), packed P; zero accums.
// P layout (tile-linear): tile T = codes [T*32,T*32+32), 32 tiles.
// chunk c = nt*8+kk. o = ((T*16+c)*64+lane)*8+j; code = T*32+nt*16+(lane&15),
// d = (lane>>4)*8 + kk*32 + j. Each 1KB chunk lane-linear (GLL-ready).
// grid 1024 x 256
__global__ void k_prep(const float* __restrict__ E, float* __restrict__ e2,
                       float* __restrict__ e2p, float* __restrict__ Et,
                       _Float16* __restrict__ P,
                       int* __restrict__ counts, double* __restrict__ loss,
                       int* __restrict__ rcnt) {
    int b = blockIdx.x, t = threadIdx.x;
    __shared__ double red[256];
    float v = E[b * DIM + t];
    red[t] = (double)v * (double)v;

    {   // packed B-stream write (tile-linear)
        int o    = b * 256 + t;
        int j    = o & 7;
        int lane = (o >> 3) & 63;
        int c    = (o >> 9) & 15;      // chunk within tile
        int T    = o >> 13;            // tile 0..31
        int nt = c >> 3, kk = c & 7;
        int code = T * 32 + nt * 16 + (lane & 15);
        int d    = (lane >> 4) * 8 + kk * 32 + j;
        P[o] = (_Float16)(E[code * DIM + d] * 1024.0f);   // exact scaling, RN
    }

    __syncthreads();
    for (int s = 128; s > 0; s >>= 1) {
        if (t < s) red[t] += red[t + s];
        __syncthreads();
    }
    if (t == 0) { e2[b] = (float)red[0]; e2p[b] = (float)(red[0] * 1048576.0); }

    int o = b * 256 + t;
    int d = o >> 10, k = o & 1023;
    Et[o] = E[k * DIM + d];

    if (b < 4) counts[b * 256 + t] = 0;
    if (b == 0 && t == 0) { *loss = 0.0; *rcnt = 0; }
}

// ---------------------------------------------------------------------------
// main (r21-exact, best measured 70µs x3): A-in-registers GEMM, RPB=128,
// 3-slot B rotation with counted vmcnt + raw s_barrier pipeline.
// Numerics bit-identical to r8-r25.
// OCCUPANCY NOTE (r4-r7,r16,r22): no min-waves bound (spills); RPB=128 is
// the optimum of the bytes-per-row vs waves/CU trade (r20/r21/r22 curve).
// grid 512 x 256
__global__ void __launch_bounds__(256)
k_main(const float* __restrict__ X, const _Float16* __restrict__ P,
       const float* __restrict__ e2p,
       int* __restrict__ idx_ws, int* __restrict__ rlist,
       int* __restrict__ rcnt) {
    __shared__ __align__(16) char sAll[53248];
    const int tid  = threadIdx.x;
    const int wid  = tid >> 6;
    const int lane = tid & 63;
    const int c16  = lane & 15;
    const int kg   = lane >> 4;
    const int rb   = blockIdx.x * RPB;

    char* sX = sAll;
    char* sB = sAll;
    const float* sE2 = (const float*)(sAll + LDS_E2);

    ((f32x4*)(sAll + LDS_E2))[tid] = ((const f32x4*)e2p)[tid];

    // ---- A-load phase 1: rows 0..63 -> LDS f16, waves 0,1 grab A regs ----
    {
        const f32x4* Xg = (const f32x4*)(X + (size_t)rb * DIM);
        #pragma unroll
        for (int it = 0; it < 16; ++it) {
            int f = it * 256 + tid;
            int row = f >> 6, d4 = f & 63;
            f32x4 v = __builtin_nontemporal_load(&Xg[(size_t)row * 64 + d4]);
            half4 hh = {(_Float16)v[0], (_Float16)v[1], (_Float16)v[2], (_Float16)v[3]};
            *(half4*)(sX + row * ROWB + d4 * 8) = hh;
        }
    }
    __syncthreads();
    half8 ar[2][8];
    if (wid < 2) {
        #pragma unroll
        for (int mt = 0; mt < 2; ++mt)
            #pragma unroll
            for (int kk = 0; kk < 8; ++kk)
                ar[mt][kk] = *(const half8*)(sX + (wid * 32 + mt * 16 + c16) * ROWB
                                             + kk * 64 + kg * 16);
    }
    __syncthreads();
    // ---- A-load phase 2: rows 64..127, waves 2,3 grab A regs ----
    {
        const f32x4* Xg = (const f32x4*)(X + (size_t)(rb + 64) * DIM);
        #pragma unroll
        for (int it = 0; it < 16; ++it) {
            int f = it * 256 + tid;
            int row = f >> 6, d4 = f & 63;
            f32x4 v = __builtin_nontemporal_load(&Xg[(size_t)row * 64 + d4]);
            half4 hh = {(_Float16)v[0], (_Float16)v[1], (_Float16)v[2], (_Float16)v[3]};
            *(half4*)(sX + row * ROWB + d4 * 8) = hh;
        }
    }
    __syncthreads();
    if (wid >= 2) {
        #pragma unroll
        for (int mt = 0; mt < 2; ++mt)
            #pragma unroll
            for (int kk = 0; kk < 8; ++kk)
                ar[mt][kk] = *(const half8*)(sX + ((wid - 2) * 32 + mt * 16 + c16) * ROWB
                                             + kk * 64 + kg * 16);
    }
    __syncthreads();

#define STAGE(T)                                                                             \
    {                                                                                        \
        const char* src_ = (const char*)P + (size_t)(T) * 16384 + (size_t)(wid * 4) * 1024   \
                           + (size_t)lane * 16;                                              \
        char* dst_ = sB + ((T) % 3) * 16384 + (wid * 4) * 1024;                              \
        __builtin_amdgcn_global_load_lds((const __attribute__((address_space(1))) unsigned int*)(src_),          \
                                         (__attribute__((address_space(3))) unsigned int*)(dst_), 16, 0, 0);     \
        __builtin_amdgcn_global_load_lds((const __attribute__((address_space(1))) unsigned int*)(src_ + 1024),   \
                                         (__attribute__((address_space(3))) unsigned int*)(dst_ + 1024), 16, 0, 0);\
        __builtin_amdgcn_global_load_lds((const __attribute__((address_space(1))) unsigned int*)(src_ + 2048),   \
                                         (__attribute__((address_space(3))) unsigned int*)(dst_ + 2048), 16, 0, 0);\
        __builtin_amdgcn_global_load_lds((const __attribute__((address_space(1))) unsigned int*)(src_ + 3072),   \
                                         (__attribute__((address_space(3))) unsigned int*)(dst_ + 3072), 16, 0, 0);\
    }
#define SB0 __builtin_amdgcn_sched_barrier(0)

    float tb1[8], tb2[8];
    int   ti1[8];
    #pragma unroll
    for (int i = 0; i < 8; ++i) { tb1[i] = 3.4e38f; tb2[i] = 3.4e38f; ti1[i] = 0; }

    f32x4 acc[2][2];

    STAGE(0); STAGE(1);
    SB0;

    #pragma unroll 2
    for (int T = 0; T < 32; ++T) {
        if (T <= 30) { asm volatile("s_waitcnt vmcnt(4)" ::: "memory"); }
        else         { asm volatile("s_waitcnt vmcnt(0)" ::: "memory"); }
        SB0;
        __builtin_amdgcn_s_barrier();
        SB0;
        if (T < 30) STAGE(T + 2);
        SB0;

        #pragma unroll
        for (int mt = 0; mt < 2; ++mt)
            #pragma unroll
            for (int nt = 0; nt < 2; ++nt) acc[mt][nt] = 0.0f;

        const char* bbuf = sB + (T % 3) * 16384 + (size_t)lane * 16;
        #pragma unroll
        for (int kk = 0; kk < 8; ++kk) {
            half8 b0 = *(const half8*)(bbuf + (0 * 8 + kk) * 1024);
            half8 b1 = *(const half8*)(bbuf + (1 * 8 + kk) * 1024);
            acc[0][0] = __builtin_amdgcn_mfma_f32_16x16x32_f16(ar[0][kk], b0, acc[0][0], 0, 0, 0);
            acc[0][1] = __builtin_amdgcn_mfma_f32_16x16x32_f16(ar[0][kk], b1, acc[0][1], 0, 0, 0);
            acc[1][0] = __builtin_amdgcn_mfma_f32_16x16x32_f16(ar[1][kk], b0, acc[1][0], 0, 0, 0);
            acc[1][1] = __builtin_amdgcn_mfma_f32_16x16x32_f16(ar[1][kk], b1, acc[1][1], 0, 0, 0);
        }

        #pragma unroll
        for (int nt = 0; nt < 2; ++nt) {
            const int code = T * 32 + nt * 16 + c16;
            const float e2v = sE2[code];
            #pragma unroll
            for (int mt = 0; mt < 2; ++mt)
                #pragma unroll
                for (int r = 0; r < 4; ++r) {
                    float sc = fmaf(-2048.0f, acc[mt][nt][r], e2v);
                    int ix = mt * 4 + r;
                    tb2[ix] = __builtin_amdgcn_fmed3f(tb1[ix], tb2[ix], sc);
                    bool lt = sc < tb1[ix];
                    tb1[ix] = lt ? sc : tb1[ix];
                    ti1[ix] = lt ? code : ti1[ix];
                }
        }
        SB0;
    }
#undef STAGE
#undef SB0

    #pragma unroll
    for (int ix = 0; ix < 8; ++ix) {
        float v1 = tb1[ix], v2 = tb2[ix];
        int   j1 = ti1[ix];
        #pragma unroll
        for (int m = 1; m < 16; m <<= 1) {
            float ov1 = __shfl_xor(v1, m, 64);
            int   oj1 = __shfl_xor(j1, m, 64);
            float ov2 = __shfl_xor(v2, m, 64);
            bool take = (ov1 < v1) || (ov1 == v1 && oj1 < j1);
            float losr = take ? v1 : ov1;
            v1 = take ? ov1 : v1;
            j1 = take ? oj1 : j1;
            v2 = fminf(fminf(v2, ov2), losr);
        }
        tb1[ix] = v1; tb2[ix] = v2; ti1[ix] = j1;
    }
    if (c16 == 0) {
        #pragma unroll
        for (int ix = 0; ix < 8; ++ix) {
            int row = wid * 32 + (ix >> 2) * 16 + kg * 4 + (ix & 3);
            int g = rb + row;
            idx_ws[g] = ti1[ix];
            if (tb2[ix] - tb1[ix] < TAUP) {
                int slot = atomicAdd(rcnt, 1);
                rlist[slot] = g;
            }
        }
    }
}

// ---------------------------------------------------------------------------
// refine: exact reference-fp32 replication, 4 rows per Et sweep, d-loop
// unrolled x4, grid 1024 (best of the four refine structures tried:
// r15=58.7µs vs r18=94.5, r23=74.8, r24=~60 incl. extra passes). fp64
// accumulation order per accumulator UNCHANGED from all passing rounds.
// grid 1024 x 256
__launch_bounds__(256, 1)
__global__ void k_refine(const float* __restrict__ X, const float* __restrict__ Et,
                         const float* __restrict__ e2,
                         const int* __restrict__ rlist, const int* __restrict__ rcnt,
                         int* __restrict__ idx_ws) {
    __shared__ float xs[4][256];
    __shared__ float sbv[4][256];
    __shared__ int   sbi[4][256];
    __shared__ float x2s[4];
    __shared__ int   rows[4];
    const int cnt = *rcnt;
    const int t = threadIdx.x;
    for (int base = blockIdx.x * 4; base < cnt; base += gridDim.x * 4) {
        __syncthreads();
        if (t < 4) {
            int e = base + t;
            rows[t] = rlist[e < cnt ? e : (cnt - 1)];
        }
        __syncthreads();
        ((float4*)xs[t >> 6])[t & 63] =
            ((const float4*)(X + (size_t)rows[t >> 6] * DIM))[t & 63];
        __syncthreads();
        if (t < 4) {
            double s = 0.0;
            for (int d = 0; d < DIM; ++d) { double xv = (double)xs[t][d]; s += xv * xv; }
            x2s[t] = (float)s;
        }
        __syncthreads();

        double a0[4], a1[4], a2[4], a3[4];
        #pragma unroll
        for (int r = 0; r < 4; ++r) { a0[r] = 0.0; a1[r] = 0.0; a2[r] = 0.0; a3[r] = 0.0; }
        #pragma unroll 4
        for (int d = 0; d < DIM; ++d) {
            double e0 = (double)Et[d * KCODES + t];
            double e1 = (double)Et[d * KCODES + 256 + t];
            double e2d = (double)Et[d * KCODES + 512 + t];
            double e3 = (double)Et[d * KCODES + 768 + t];
            #pragma unroll
            for (int r = 0; r < 4; ++r) {
                double xv = (double)xs[r][d];
                a0[r] += xv * e0;
                a1[r] += xv * e1;
                a2[r] += xv * e2d;
                a3[r] += xv * e3;
            }
        }

        const float eA = e2[t], eB = e2[256 + t], eC = e2[512 + t], eD = e2[768 + t];
        #pragma unroll
        for (int r = 0; r < 4; ++r) {
            float best = 3.4e38f; int bk = 0;
            float x2 = x2s[r];
            { float d2 = fmaf(-2.f, (float)a0[r], x2 + eA); if (d2 < best) { best = d2; bk = t; } }
            { float d2 = fmaf(-2.f, (float)a1[r], x2 + eB); if (d2 < best) { best = d2; bk = 256 + t; } }
            { float d2 = fmaf(-2.f, (float)a2[r], x2 + eC); if (d2 < best) { best = d2; bk = 512 + t; } }
            { float d2 = fmaf(-2.f, (float)a3[r], x2 + eD); if (d2 < best) { best = d2; bk = 768 + t; } }
            sbv[r][t] = best; sbi[r][t] = bk;
        }
        __syncthreads();
        {
            const int w = t >> 6, lane = t & 63;
            float v = sbv[w][lane];     int id = sbi[w][lane];
            #pragma unroll
            for (int c = 1; c < 4; ++c) {
                float ov = sbv[w][lane + 64 * c]; int oi = sbi[w][lane + 64 * c];
                if (ov < v || (ov == v && oi < id)) { v = ov; id = oi; }
            }
            #pragma unroll
            for (int m = 1; m < 64; m <<= 1) {
                float ov = __shfl_xor(v, m, 64);
                int   oi = __shfl_xor(id, m, 64);
                if (ov < v || (ov == v && oi < id)) { v = ov; id = oi; }
            }
            if (lane == 0 && base + w < cnt) idx_ws[rows[w]] = id;
        }
    }
}

// ---------------------------------------------------------------------------
// out: quantized rows, index output, loss, histogram. One fp64 atomic/block.
// NOTE (r25 lesson): do NOT fuse fin here via last-block ticket — the
// required __threadfence per block taxes the 64MB of stores (~3x k_out cost).
// grid 1024 x 256
__launch_bounds__(256)
__global__ void k_out(const float* __restrict__ X, const float* __restrict__ E,
                      const int* __restrict__ idx_ws, float* __restrict__ out,
                      int* __restrict__ counts, double* __restrict__ loss) {
    const int tid = threadIdx.x;
    const int w = tid >> 6, lane = tid & 63;
    const int rbase = blockIdx.x * 64;
    double ls = 0.0;
    #pragma unroll 4
    for (int it = 0; it < 16; ++it) {
        const int row = rbase + it * 4 + w;
        const int k = idx_ws[row];
        float4 q = ((const float4*)(E + (size_t)k * DIM))[lane];
        float4 x = ((const float4*)(X + (size_t)row * DIM))[lane];
        ((float4*)(out + (size_t)row * DIM))[lane] = q;
        double d0 = (double)q.x - (double)x.x;
        double d1 = (double)q.y - (double)x.y;
        double d2 = (double)q.z - (double)x.z;
        double d3 = (double)q.w - (double)x.w;
        ls += d0 * d0 + d1 * d1 + d2 * d2 + d3 * d3;
        if (lane == 0) {
            atomicAdd(&counts[k], 1);
            out[OUT_IDX + row] = (float)k;
        }
    }
    __shared__ double red[256];
    red[tid] = ls;
    __syncthreads();
    for (int s = 128; s > 0; s >>= 1) {
        if (tid < s) red[tid] += red[tid + s];
        __syncthreads();
    }
    if (tid == 0) atomicAdd(loss, red[0]);
}

// ---------------------------------------------------------------------------
// fin: scalars
__global__ void k_fin(const int* __restrict__ counts, const double* __restrict__ loss,
                      float* __restrict__ out) {
    int t = threadIdx.x;
    __shared__ double red[256];
    double h = 0.0;
    #pragma unroll
    for (int i = 0; i < 4; ++i) {
        double p = (double)counts[t + i * 256] / (double)N_ROWS;
        h += p * log(p + 1e-10);
    }
    red[t] = h;
    __syncthreads();
    for (int s = 128; s > 0; s >>= 1) {
        if (t < s) red[t] += red[t + s];
        __syncthreads();
    }
    if (t == 0) {
        out[OUT_PERP] = (float)exp(-red[0]);
        out[OUT_LOSS] = (float)((*loss) / (double)Q_SIZE * 1.25);
    }
}

// ---------------------------------------------------------------------------
extern "C" void kernel_launch(void* const* d_in, const int* in_sizes, int n_in,
                              void* d_out, int out_size, void* d_ws, size_t ws_size,
                              hipStream_t stream) {
    (void)in_sizes; (void)n_in; (void)out_size; (void)ws_size;
    const float* X = (const float*)d_in[0];
    const float* E = (const float*)d_in[1];
    float* out = (float*)d_out;
    char* ws = (char*)d_ws;

    double*    loss   = (double*)(ws + WS_LOSS);
    int*       rcnt   = (int*)(ws + WS_RCNT);
    float*     e2     = (float*)(ws + WS_E2);
    float*     e2p    = (float*)(ws + WS_E2P);
    int*       counts = (int*)(ws + WS_COUNTS);
    int*       idx_ws = (int*)(ws + WS_IDX);
    int*       rlist  = (int*)(ws + WS_RLIST);
    float*     Et     = (float*)(ws + WS_ET);
    _Float16*  Pp     = (_Float16*)(ws + WS_P);

    k_prep<<<1024, 256, 0, stream>>>(E, e2, e2p, Et, Pp, counts, loss, rcnt);
    k_main<<<N_ROWS / RPB, 256, 0, stream>>>(X, Pp, e2p, idx_ws, rlist, rcnt);
    k_refine<<<1024, 256, 0, stream>>>(X, Et, e2, rlist, rcnt, idx_ws);
    k_out<<<1024, 256, 0, stream>>>(X, E, idx_ws, out, counts, loss);
    k_fin<<<1, 256, 0, stream>>>(counts, loss, out);
}